// Round 7
// baseline (316.035 us; speedup 1.0000x reference)
//
#include <hip/hip_runtime.h>
#include <cstdint>
#include <cstddef>

typedef int int32x4  __attribute__((ext_vector_type(4)));
typedef int int32x16 __attribute__((ext_vector_type(16)));

#define AS1 __attribute__((address_space(1)))
#define AS3 __attribute__((address_space(3)))

__device__ __forceinline__ void gload_lds16(const void* g, void* l) {
    __builtin_amdgcn_global_load_lds((const AS1 void*)g, (AS3 void*)l, 16, 0, 0);
}

#define MFMA_I8(a, b, c) __builtin_amdgcn_mfma_i32_32x32x32_i8((a), (b), (c), 0, 0, 0)

// ---------------------------------------------------------------------------
// Fused quant kernel (frozen r6 version — it cut the quant path ~9us).
// Blocks [0,4096): x-rows. Blocks [4096,5120): y 256n x 64k coalesced tiles.
// ---------------------------------------------------------------------------
__global__ __launch_bounds__(256) void quant_xy(const float* __restrict__ x,
                                                const float* __restrict__ y,
                                                signed char* __restrict__ A8,
                                                signed char* __restrict__ B8T,
                                                int* __restrict__ rs,
                                                int* __restrict__ sy) {
    const int t = threadIdx.x;
    if (blockIdx.x < 4096) {
        const int row = blockIdx.x;
        const float4* xr = (const float4*)(x + (size_t)row * 4096);
        char4* ar = (char4*)(A8 + (size_t)row * 4096);
        int s = 0;
#pragma unroll
        for (int i = 0; i < 4; i++) {
            const int idx = i * 256 + t;
            float4 v = xr[idx];
            int a0 = (int)v.x, a1 = (int)v.y, a2 = (int)v.z, a3 = (int)v.w;
            s += a0 + a1 + a2 + a3;
            char4 c;
            c.x = (signed char)a0; c.y = (signed char)a1;
            c.z = (signed char)a2; c.w = (signed char)a3;
            ar[idx] = c;
        }
#pragma unroll
        for (int off = 32; off > 0; off >>= 1) s += __shfl_down(s, off);
        __shared__ int wsum[4];
        if ((t & 63) == 0) wsum[t >> 6] = s;
        __syncthreads();
        if (t == 0) rs[row] = wsum[0] + wsum[1] + wsum[2] + wsum[3];
    } else {
        const int q = blockIdx.x - 4096;
        const int nt = (q & 15) * 256;
        const int kt = (q >> 4) * 64;
        __shared__ int tile_s[256 * 16];
        __shared__ int ssum[256];
        if (t < 256) ssum[t] = 0;
        __syncthreads();

        const int n4 = (t & 63) * 4;
        const int kg = (t >> 6) * 4;
        const int swzkey = t & 15;
        int s0 = 0, s1 = 0, s2 = 0, s3 = 0;
#pragma unroll
        for (int o = 0; o < 4; o++) {
            int b[4][4];
#pragma unroll
            for (int i = 0; i < 4; i++) {
                const int k = o * 16 + kg + i;
                float4 v = *(const float4*)(y + (size_t)(kt + k) * 4096 + nt + n4);
                b[i][0] = (int)v.x - 128; b[i][1] = (int)v.y - 128;
                b[i][2] = (int)v.z - 128; b[i][3] = (int)v.w - 128;
            }
            const int kd = o * 4 + (t >> 6);
            const int sw = kd ^ swzkey;
#pragma unroll
            for (int j = 0; j < 4; j++) {
                const int w = (b[0][j] & 255) | ((b[1][j] & 255) << 8) |
                              ((b[2][j] & 255) << 16) | (b[3][j] << 24);
                tile_s[(n4 + j) * 16 + sw] = w;
            }
            s0 += b[0][0] + b[1][0] + b[2][0] + b[3][0];
            s1 += b[0][1] + b[1][1] + b[2][1] + b[3][1];
            s2 += b[0][2] + b[1][2] + b[2][2] + b[3][2];
            s3 += b[0][3] + b[1][3] + b[2][3] + b[3][3];
        }
        atomicAdd(&ssum[n4 + 0], s0);
        atomicAdd(&ssum[n4 + 1], s1);
        atomicAdd(&ssum[n4 + 2], s2);
        atomicAdd(&ssum[n4 + 3], s3);
        __syncthreads();

        const int c = t & 3;
#pragma unroll
        for (int p = 0; p < 4; p++) {
            const int n = (t >> 2) + p * 64;
            const int key = (n >> 2) & 15;
            int32x4 o;
            o.x = tile_s[n * 16 + ((c * 4 + 0) ^ key)];
            o.y = tile_s[n * 16 + ((c * 4 + 1) ^ key)];
            o.z = tile_s[n * 16 + ((c * 4 + 2) ^ key)];
            o.w = tile_s[n * 16 + ((c * 4 + 3) ^ key)];
            *(int32x4*)(B8T + (size_t)(nt + n) * 4096 + kt + c * 16) = o;
        }
        if (t < 256) atomicAdd(&sy[nt + t], ssum[t]);
    }
}

// ---------------------------------------------------------------------------
// Kernel 3: int8 GEMM — A DIRECT-FROM-GLOBAL round.
// Diagnosis (r0-r6): MfmaUtil pinned 31-39% across 5 schedules. LDS pipe
// accounting: 96KB read + 32KB written per tile per CU (~1400cy) vs MFMA
// 1171cy/SIMD; A-frag reads are 64KB of it, duplicated 4x across waves
// sharing wm. Fix: de-stage A. Each lane loads its 16B A-frag straight from
// global: addr (bm+wm+i*32+mr)*4096 + kt + ks*32 + kh*16 (bit-identical
// operand bytes). L1 absorbs the 4x wave duplication (16KB/tile working
// set); A panels are L2-resident under the XCD swizzle; HBM FETCH unchanged.
// LDS: B-only 4-deep ring (64KB). LDS load 128->48KB/tile. Register cost
// net 0 vs r4 (aC[4][2]+xb+yb = 48 regs = old xa/ya/xb/yb).
// Pipelining: A(t+1) ks0 reloaded mid-body (after half0 MFMAs consume ks0),
// A(t+1) ks1 at body end -> ~1 cluster (~500cy) of latency cover; compiler
// inserts fine-grained vmcnt before first use. B-frags keep r4's cross-tile
// register double-buffer (xb read from B(t+1) during half1).
// vmcnt (10 VMEM ops/body: Bstage 2 + A-ks0 4 + A-ks1 4):
//   top of t: vmcnt(10) leaves [B(t+2), A(t)x8] => B(t),B(t+1) landed.
//   t==0: vmcnt(2) (prologue: A(0)x8,B0,B1,B2; leave B2). t==62: vmcnt(8).
//   t==63: vmcnt(0). sched_barrier(0) pins code motion around each wait.
// Geometry: BM=BN=256, BK=64, 8 waves 2Mx4N, wave tile 128x64 = 4x2 of
// 32x32x32 i8 MFMA. B XOR chunk swizzle at global source (LDS dest linear).
// Frags: A[m=lane&31][k=(lane>>5)*16+j]; C/D col=lane&31,
// row=(reg&3)+8*(reg>>2)+4*(lane>>5)  (verified r0-r6, absmax 32).
// Epilogue: C = 7.5e-4 * (P - 32*rs[m] + 66*sy[n] - 8650752)
// ---------------------------------------------------------------------------
__global__ __launch_bounds__(512, 2) void gemm_i8(const signed char* __restrict__ A8,
                                                  const signed char* __restrict__ B8T,
                                                  const int* __restrict__ rs,
                                                  const int* __restrict__ sy,
                                                  float* __restrict__ C) {
    __shared__ __align__(16) signed char Bs[4 * 16384];  // 256 rows x 64B x 4
    const int tid = threadIdx.x;
    const int lin = blockIdx.x;
    const int til = (lin & 7) * 32 + (lin >> 3);   // XCD-contiguous tiles
    const int bm = (til >> 4) * 256;
    const int bn = (til & 15) * 256;
    const int lane = tid & 63;
    const int wave = tid >> 6;
    const int wm = (wave >> 2) * 128;   // 2 m-waves x 128
    const int wn = (wave & 3) * 64;     // 4 n-waves x 64
    const int mr = lane & 31;
    const int kh = lane >> 5;

    int32x16 acc[4][2] = {};

    // B staging (thread -> row tid>>2 (+128), chunk XOR-swizzled at source)
    const int srow = tid >> 2;
    const int scol = ((tid & 3) ^ ((tid >> 3) & 3)) * 16;
    const size_t brow = (size_t)(bn + srow) * 4096 + scol;

    // B fragment LDS offsets: row = wn + j*32 + mr; chunk = ks*2 + kh;
    // phys slot = chunk ^ ((mr>>1)&3)
    int boff[2][2];
#pragma unroll
    for (int ks = 0; ks < 2; ks++) {
        const int slot = ((ks * 2 + kh) ^ ((mr >> 1) & 3)) * 16;
#pragma unroll
        for (int j = 0; j < 2; j++) boff[j][ks] = (wn + j * 32 + mr) * 64 + slot;
    }

    // A direct-load per-lane base: row (bm+wm+mr), k-offset kh*16.
    const signed char* aG = A8 + (size_t)(bm + wm + mr) * 4096 + kh * 16;

    auto stageB = [&](int buf, int kt) {
        signed char* b_dst = Bs + buf * 16384 + tid * 16;
#pragma unroll
        for (int p = 0; p < 2; p++)
            gload_lds16(B8T + brow + (size_t)p * 524288 + kt, b_dst + p * 8192);
    };

    int32x4 aC[4][2];       // A frags of current tile (reloaded in-place)
    int32x4 xb[2], yb[2];   // B frags: xb = ks0 (cross-tile), yb = ks1

    // ---- prologue ----
#pragma unroll
    for (int i = 0; i < 4; i++) {
        aC[i][0] = *(const int32x4*)(aG + (size_t)i * 131072 + 0);
        aC[i][1] = *(const int32x4*)(aG + (size_t)i * 131072 + 32);
    }
    stageB(0, 0);
    stageB(1, 64);
    stageB(2, 128);
    __builtin_amdgcn_sched_barrier(0);
    __builtin_amdgcn_s_waitcnt(0xF74);   // vmcnt(4): B(0)+A(0) landed
    __builtin_amdgcn_s_barrier();
    __builtin_amdgcn_sched_barrier(0);
    xb[0] = *(const int32x4*)(Bs + boff[0][0]);
    xb[1] = *(const int32x4*)(Bs + boff[1][0]);

#pragma unroll 1
    for (int t = 0; t < 64; ++t) {
        const signed char* Bb  = Bs + (t & 3) * 16384;        // tile t
        const signed char* Bbn = Bs + ((t + 1) & 3) * 16384;  // tile t+1
        signed char* b_dst = Bs + ((t + 3) & 3) * 16384 + tid * 16;
        const size_t gk = (size_t)(t + 3) * 64;
        const int ktn = (t + 1) * 64;

        __builtin_amdgcn_sched_barrier(0);
        if (t == 0)       __builtin_amdgcn_s_waitcnt(0xF72);  // vmcnt(2)
        else if (t == 62) __builtin_amdgcn_s_waitcnt(0xF78);  // vmcnt(8)
        else if (t == 63) __builtin_amdgcn_s_waitcnt(0xF70);  // vmcnt(0)
        else              __builtin_amdgcn_s_waitcnt(0xF7A);  // vmcnt(10)
        __builtin_amdgcn_s_barrier();
        __builtin_amdgcn_sched_barrier(0);

        // ---- half 0: read yb (B(t) ks1); stage B(t+3); MFMA aC[*][0] x xb
        yb[0] = *(const int32x4*)(Bb + boff[0][1]);
        yb[1] = *(const int32x4*)(Bb + boff[1][1]);
        if (t < 61) {
            gload_lds16(B8T + brow + gk, b_dst);
            gload_lds16(B8T + brow + 524288 + gk, b_dst + 8192);
        }
        __builtin_amdgcn_sched_barrier(0);
        __builtin_amdgcn_s_setprio(1);
        acc[0][0] = MFMA_I8(aC[0][0], xb[0], acc[0][0]);
        acc[0][1] = MFMA_I8(aC[0][0], xb[1], acc[0][1]);
        acc[1][0] = MFMA_I8(aC[1][0], xb[0], acc[1][0]);
        acc[1][1] = MFMA_I8(aC[1][0], xb[1], acc[1][1]);
        acc[2][0] = MFMA_I8(aC[2][0], xb[0], acc[2][0]);
        acc[2][1] = MFMA_I8(aC[2][0], xb[1], acc[2][1]);
        acc[3][0] = MFMA_I8(aC[3][0], xb[0], acc[3][0]);
        acc[3][1] = MFMA_I8(aC[3][0], xb[1], acc[3][1]);
        __builtin_amdgcn_s_setprio(0);

        // ---- mid: reload aC[*][0] <- A(t+1) ks0; xb <- B(t+1) ks0 ----
        if (t < 63) {
#pragma unroll
            for (int i = 0; i < 4; i++)
                aC[i][0] = *(const int32x4*)(aG + (size_t)i * 131072 + ktn);
            xb[0] = *(const int32x4*)(Bbn + boff[0][0]);
            xb[1] = *(const int32x4*)(Bbn + boff[1][0]);
        }

        // ---- half 1: MFMA aC[*][1] x yb ----
        __builtin_amdgcn_sched_barrier(0);
        __builtin_amdgcn_s_setprio(1);
        acc[0][0] = MFMA_I8(aC[0][1], yb[0], acc[0][0]);
        acc[0][1] = MFMA_I8(aC[0][1], yb[1], acc[0][1]);
        acc[1][0] = MFMA_I8(aC[1][1], yb[0], acc[1][0]);
        acc[1][1] = MFMA_I8(aC[1][1], yb[1], acc[1][1]);
        acc[2][0] = MFMA_I8(aC[2][1], yb[0], acc[2][0]);
        acc[2][1] = MFMA_I8(aC[2][1], yb[1], acc[2][1]);
        acc[3][0] = MFMA_I8(aC[3][1], yb[0], acc[3][0]);
        acc[3][1] = MFMA_I8(aC[3][1], yb[1], acc[3][1]);
        __builtin_amdgcn_s_setprio(0);

        // ---- end: reload aC[*][1] <- A(t+1) ks1 ----
        if (t < 63) {
#pragma unroll
            for (int i = 0; i < 4; i++)
                aC[i][1] = *(const int32x4*)(aG + (size_t)i * 131072 + ktn + 32);
        }
    }

    // Epilogue. C/D: col = lane&31, row = (reg&3) + 8*(reg>>2) + 4*kh
#pragma unroll
    for (int i = 0; i < 4; i++) {
#pragma unroll
        for (int r = 0; r < 16; r++) {
            const int gm = bm + wm + i * 32 + (r & 3) + 8 * (r >> 2) + 4 * kh;
            const int rcorr = -32 * rs[gm] - 8650752;
#pragma unroll
            for (int j = 0; j < 2; j++) {
                const int gn = bn + wn + j * 32 + mr;
                const int v = acc[i][j][r] + rcorr + 66 * sy[gn];
                C[(size_t)gm * 4096 + gn] = 7.5e-4f * (float)v;
            }
        }
    }
}

// ---------------------------------------------------------------------------
extern "C" void kernel_launch(void* const* d_in, const int* in_sizes, int n_in,
                              void* d_out, int out_size, void* d_ws, size_t ws_size,
                              hipStream_t stream) {
    const float* x = (const float*)d_in[0];  // [4096,4096] int8-valued
    const float* y = (const float*)d_in[1];  // [4096,4096] uint8-valued
    float* out = (float*)d_out;

    char* ws = (char*)d_ws;
    signed char* A8  = (signed char*)ws;                         // 16 MiB
    signed char* B8T = (signed char*)(ws + (16u << 20));         // 16 MiB
    int* rs = (int*)(ws + (32u << 20));                          // 16 KiB
    int* sy = (int*)(ws + (32u << 20) + (16u << 10));            // 16 KiB

    hipMemsetAsync(sy, 0, 4096 * sizeof(int), stream);
    quant_xy<<<5120, 256, 0, stream>>>(x, y, A8, B8T, rs, sy);
    gemm_i8<<<256, 512, 0, stream>>>(A8, B8T, rs, sy, out);
}

// Round 9
// 245.364 us; speedup vs baseline: 1.2880x; 1.2880x over previous
//
#include <hip/hip_runtime.h>
#include <cstdint>
#include <cstddef>

typedef int int32x4  __attribute__((ext_vector_type(4)));
typedef int int32x16 __attribute__((ext_vector_type(16)));

#define AS1 __attribute__((address_space(1)))
#define AS3 __attribute__((address_space(3)))

__device__ __forceinline__ void gload_lds16(const void* g, void* l) {
    __builtin_amdgcn_global_load_lds((const AS1 void*)g, (AS3 void*)l, 16, 0, 0);
}

#define MFMA_I8(a, b, c) __builtin_amdgcn_mfma_i32_32x32x32_i8((a), (b), (c), 0, 0, 0)

// ---------------------------------------------------------------------------
// Fused quant kernel (frozen r6 version).
// Blocks [0,4096): x-rows. Blocks [4096,5120): y 256n x 64k coalesced tiles.
// ---------------------------------------------------------------------------
__global__ __launch_bounds__(256) void quant_xy(const float* __restrict__ x,
                                                const float* __restrict__ y,
                                                signed char* __restrict__ A8,
                                                signed char* __restrict__ B8T,
                                                int* __restrict__ rs,
                                                int* __restrict__ sy) {
    const int t = threadIdx.x;
    if (blockIdx.x < 4096) {
        const int row = blockIdx.x;
        const float4* xr = (const float4*)(x + (size_t)row * 4096);
        char4* ar = (char4*)(A8 + (size_t)row * 4096);
        int s = 0;
#pragma unroll
        for (int i = 0; i < 4; i++) {
            const int idx = i * 256 + t;
            float4 v = xr[idx];
            int a0 = (int)v.x, a1 = (int)v.y, a2 = (int)v.z, a3 = (int)v.w;
            s += a0 + a1 + a2 + a3;
            char4 c;
            c.x = (signed char)a0; c.y = (signed char)a1;
            c.z = (signed char)a2; c.w = (signed char)a3;
            ar[idx] = c;
        }
#pragma unroll
        for (int off = 32; off > 0; off >>= 1) s += __shfl_down(s, off);
        __shared__ int wsum[4];
        if ((t & 63) == 0) wsum[t >> 6] = s;
        __syncthreads();
        if (t == 0) rs[row] = wsum[0] + wsum[1] + wsum[2] + wsum[3];
    } else {
        const int q = blockIdx.x - 4096;
        const int nt = (q & 15) * 256;
        const int kt = (q >> 4) * 64;
        __shared__ int tile_s[256 * 16];
        __shared__ int ssum[256];
        if (t < 256) ssum[t] = 0;
        __syncthreads();

        const int n4 = (t & 63) * 4;
        const int kg = (t >> 6) * 4;
        const int swzkey = t & 15;
        int s0 = 0, s1 = 0, s2 = 0, s3 = 0;
#pragma unroll
        for (int o = 0; o < 4; o++) {
            int b[4][4];
#pragma unroll
            for (int i = 0; i < 4; i++) {
                const int k = o * 16 + kg + i;
                float4 v = *(const float4*)(y + (size_t)(kt + k) * 4096 + nt + n4);
                b[i][0] = (int)v.x - 128; b[i][1] = (int)v.y - 128;
                b[i][2] = (int)v.z - 128; b[i][3] = (int)v.w - 128;
            }
            const int kd = o * 4 + (t >> 6);
            const int sw = kd ^ swzkey;
#pragma unroll
            for (int j = 0; j < 4; j++) {
                const int w = (b[0][j] & 255) | ((b[1][j] & 255) << 8) |
                              ((b[2][j] & 255) << 16) | (b[3][j] << 24);
                tile_s[(n4 + j) * 16 + sw] = w;
            }
            s0 += b[0][0] + b[1][0] + b[2][0] + b[3][0];
            s1 += b[0][1] + b[1][1] + b[2][1] + b[3][1];
            s2 += b[0][2] + b[1][2] + b[2][2] + b[3][2];
            s3 += b[0][3] + b[1][3] + b[2][3] + b[3][3];
        }
        atomicAdd(&ssum[n4 + 0], s0);
        atomicAdd(&ssum[n4 + 1], s1);
        atomicAdd(&ssum[n4 + 2], s2);
        atomicAdd(&ssum[n4 + 3], s3);
        __syncthreads();

        const int c = t & 3;
#pragma unroll
        for (int p = 0; p < 4; p++) {
            const int n = (t >> 2) + p * 64;
            const int key = (n >> 2) & 15;
            int32x4 o;
            o.x = tile_s[n * 16 + ((c * 4 + 0) ^ key)];
            o.y = tile_s[n * 16 + ((c * 4 + 1) ^ key)];
            o.z = tile_s[n * 16 + ((c * 4 + 2) ^ key)];
            o.w = tile_s[n * 16 + ((c * 4 + 3) ^ key)];
            *(int32x4*)(B8T + (size_t)(nt + n) * 4096 + kt + c * 16) = o;
        }
        if (t < 256) atomicAdd(&sy[nt + t], ssum[t]);
    }
}

// ---------------------------------------------------------------------------
// Kernel 3: int8 GEMM — BLOCK-TLP round, take 2.
// r8 FAILED on a staging bug: global_load_lds writes LDS at wave-uniform
// base + lane*16 (m104/m108); the tid*32 A-dst pattern scrambled the tile.
// FIX: A staged exactly like B — per instr p, thread tid -> LDS
// buf*8192 + p*4096 + tid*16 => row p*64+(tid>>2), phys chunk tid&3,
// source chunk (tid&3)^((tid>>3)&3) (for row r: (tid>>3)&3 == (r>>1)&3;
// p*64 contributes 0 mod 4 to (row>>1)&3). Bit-identical layout to aoff.
// Hypothesis unchanged (untested due to r8 bug): r4's residual stall is the
// single block's unified barrier domain; 2 independent 4-wave blocks/CU
// (tile 128Mx256N, 72KB 3-ring) decouple barriers so one block's MFMA
// covers the other's staging stall. Per-wave structure identical to r4
// (wave-tile 128x64, 16 MFMA/tile, cross-tile register frag pipeline).
// vmcnt discipline (6 gloads/tile: 2 A + 4 B; in-order retirement):
//  top of t: vmcnt(6) => tile t landed; barrier => cross-wave visible.
//  mid of t (after issuing stage(t+2), 12 outstanding): vmcnt(6) => own
//    stage(t+1) landed; s_barrier => ALL waves' t+1 landed; then read
//    xa/xb <- tile t+1 (feeds next tile's half0 -> no lgkm stall on MFMA).
//  t==62 mid: vmcnt(0) (no stage(64)). t==63: no refill.
// Geometry: 512 blocks (=2/CU), XCD swizzle til=(lin&7)*64+(lin>>3)
// (bijective, 512%8==0); bm=(til>>4)*128, bn=(til&15)*256; 4 n-waves
// (wm=0, wn=wave*64). Frags: A[m=lane&31][k=(lane>>5)*16+j]; C/D
// col=lane&31, row=(reg&3)+8*(reg>>2)+4*(lane>>5) (verified r0-r7).
// Epilogue: C = 7.5e-4 * (P - 32*rs[m] + 66*sy[n] - 8650752)
// ---------------------------------------------------------------------------
__global__ __launch_bounds__(256, 2) void gemm_i8(const signed char* __restrict__ A8,
                                                  const signed char* __restrict__ B8T,
                                                  const int* __restrict__ rs,
                                                  const int* __restrict__ sy,
                                                  float* __restrict__ C) {
    __shared__ __align__(16) signed char As[3 * 8192];   // 128 rows x 64B x 3
    __shared__ __align__(16) signed char Bs[3 * 16384];  // 256 rows x 64B x 3
    const int tid = threadIdx.x;
    const int lin = blockIdx.x;
    const int til = (lin & 7) * 64 + (lin >> 3);   // XCD-contiguous tiles
    const int bm = (til >> 4) * 128;
    const int bn = (til & 15) * 256;
    const int lane = tid & 63;
    const int wave = tid >> 6;
    const int wn = wave * 64;           // 4 n-waves; wm = 0
    const int mr = lane & 31;
    const int kh = lane >> 5;

    int32x16 acc[4][2] = {};

    // A and B staging share the proven formula: thread tid -> row tid>>2
    // (+64p via p*262144), source chunk (tid&3)^((tid>>3)&3), dst tid*16
    // (+p*4096) — matches global_load_lds' uniform-base + lane*16 layout.
    const size_t srowoff = (size_t)(tid >> 2) * 4096 +
                           (((tid & 3) ^ ((tid >> 3) & 3)) * 16);
    const size_t arow = (size_t)bm * 4096 + srowoff;
    const size_t brow = (size_t)bn * 4096 + srowoff;

    // fragment LDS offsets: slot = (ks*2+kh) ^ ((mr>>1)&3)
    int aoff[4][2], boff[2][2];
#pragma unroll
    for (int ks = 0; ks < 2; ks++) {
        const int slot = ((ks * 2 + kh) ^ ((mr >> 1) & 3)) * 16;
#pragma unroll
        for (int i = 0; i < 4; i++) aoff[i][ks] = (i * 32 + mr) * 64 + slot;
#pragma unroll
        for (int j = 0; j < 2; j++) boff[j][ks] = (wn + j * 32 + mr) * 64 + slot;
    }

    auto stage = [&](int buf, int kt) {   // 6 gloads: 2 A + 4 B
        signed char* a_dst = As + buf * 8192 + tid * 16;
#pragma unroll
        for (int p = 0; p < 2; p++)
            gload_lds16(A8 + arow + (size_t)p * 262144 + kt, a_dst + p * 4096);
        signed char* b_dst = Bs + buf * 16384 + tid * 16;
#pragma unroll
        for (int p = 0; p < 4; p++)
            gload_lds16(B8T + brow + (size_t)p * 262144 + kt, b_dst + p * 4096);
    };

    stage(0, 0);
    stage(1, 64);
    // waitcnt imm: vmcnt[3:0]=bits0-3, vmcnt[5:4]=bits14-15.
    // 0xF76 = vmcnt(6), 0xF70 = vmcnt(0).
    __builtin_amdgcn_s_waitcnt(0xF76);   // tile 0 landed (tile 1 in flight)
    __builtin_amdgcn_s_barrier();
    __builtin_amdgcn_sched_barrier(0);

    int32x4 xa[4], xb[2];   // ks0 frags (cross-tile pipelined)
    int32x4 ya[4], yb[2];   // ks1 frags of current tile
#pragma unroll
    for (int i = 0; i < 4; i++) xa[i] = *(const int32x4*)(As + aoff[i][0]);
#pragma unroll
    for (int j = 0; j < 2; j++) xb[j] = *(const int32x4*)(Bs + boff[j][0]);

#pragma unroll 1
    for (int t = 0; t < 64; ++t) {
        const signed char* Ab  = As + (t % 3) * 8192;         // tile t
        const signed char* Bb  = Bs + (t % 3) * 16384;
        const signed char* Abn = As + ((t + 1) % 3) * 8192;   // tile t+1
        const signed char* Bbn = Bs + ((t + 1) % 3) * 16384;

        __builtin_amdgcn_sched_barrier(0);
        __builtin_amdgcn_s_waitcnt(0xF76);   // tile t landed (in-order retire)
        __builtin_amdgcn_s_barrier();        // cross-wave: tile t visible
        __builtin_amdgcn_sched_barrier(0);

        // ---- read ks1 frags of tile t; issue stage(t+2) ----
#pragma unroll
        for (int i = 0; i < 4; i++) ya[i] = *(const int32x4*)(Ab + aoff[i][1]);
#pragma unroll
        for (int j = 0; j < 2; j++) yb[j] = *(const int32x4*)(Bb + boff[j][1]);
        if (t < 62) stage((t + 2) % 3, (t + 2) * 64);
        __builtin_amdgcn_sched_barrier(0);

        // ---- half 0: MFMA xa/xb (preloaded last tile; no lgkm stall) ----
        __builtin_amdgcn_s_setprio(1);
        acc[0][0] = MFMA_I8(xa[0], xb[0], acc[0][0]);
        acc[0][1] = MFMA_I8(xa[0], xb[1], acc[0][1]);
        acc[1][0] = MFMA_I8(xa[1], xb[0], acc[1][0]);
        acc[1][1] = MFMA_I8(xa[1], xb[1], acc[1][1]);
        acc[2][0] = MFMA_I8(xa[2], xb[0], acc[2][0]);
        acc[2][1] = MFMA_I8(xa[2], xb[1], acc[2][1]);
        acc[3][0] = MFMA_I8(xa[3], xb[0], acc[3][0]);
        acc[3][1] = MFMA_I8(xa[3], xb[1], acc[3][1]);
        __builtin_amdgcn_s_setprio(0);
        __builtin_amdgcn_sched_barrier(0);

        // ---- mid: tile t+1 ready? own vmcnt + cross-wave barrier ----
        if (t < 63) {
            if (t == 62) __builtin_amdgcn_s_waitcnt(0xF70);  // no stage(64)
            else         __builtin_amdgcn_s_waitcnt(0xF76);  // t+1 landed (own)
            __builtin_amdgcn_s_barrier();                    // all waves
            __builtin_amdgcn_sched_barrier(0);
#pragma unroll
            for (int i = 0; i < 4; i++) xa[i] = *(const int32x4*)(Abn + aoff[i][0]);
#pragma unroll
            for (int j = 0; j < 2; j++) xb[j] = *(const int32x4*)(Bbn + boff[j][0]);
        }
        __builtin_amdgcn_sched_barrier(0);

        // ---- half 1: MFMA ya/yb ----
        __builtin_amdgcn_s_setprio(1);
        acc[0][0] = MFMA_I8(ya[0], yb[0], acc[0][0]);
        acc[0][1] = MFMA_I8(ya[0], yb[1], acc[0][1]);
        acc[1][0] = MFMA_I8(ya[1], yb[0], acc[1][0]);
        acc[1][1] = MFMA_I8(ya[1], yb[1], acc[1][1]);
        acc[2][0] = MFMA_I8(ya[2], yb[0], acc[2][0]);
        acc[2][1] = MFMA_I8(ya[2], yb[1], acc[2][1]);
        acc[3][0] = MFMA_I8(ya[3], yb[0], acc[3][0]);
        acc[3][1] = MFMA_I8(ya[3], yb[1], acc[3][1]);
        __builtin_amdgcn_s_setprio(0);
    }

    // Epilogue. C/D: col = lane&31, row = (reg&3) + 8*(reg>>2) + 4*kh
#pragma unroll
    for (int i = 0; i < 4; i++) {
#pragma unroll
        for (int r = 0; r < 16; r++) {
            const int gm = bm + i * 32 + (r & 3) + 8 * (r >> 2) + 4 * kh;
            const int rcorr = -32 * rs[gm] - 8650752;
#pragma unroll
            for (int j = 0; j < 2; j++) {
                const int gn = bn + wn + j * 32 + mr;
                const int v = acc[i][j][r] + rcorr + 66 * sy[gn];
                C[(size_t)gm * 4096 + gn] = 7.5e-4f * (float)v;
            }
        }
    }
}

// ---------------------------------------------------------------------------
extern "C" void kernel_launch(void* const* d_in, const int* in_sizes, int n_in,
                              void* d_out, int out_size, void* d_ws, size_t ws_size,
                              hipStream_t stream) {
    const float* x = (const float*)d_in[0];  // [4096,4096] int8-valued
    const float* y = (const float*)d_in[1];  // [4096,4096] uint8-valued
    float* out = (float*)d_out;

    char* ws = (char*)d_ws;
    signed char* A8  = (signed char*)ws;                         // 16 MiB
    signed char* B8T = (signed char*)(ws + (16u << 20));         // 16 MiB
    int* rs = (int*)(ws + (32u << 20));                          // 16 KiB
    int* sy = (int*)(ws + (32u << 20) + (16u << 10));            // 16 KiB

    hipMemsetAsync(sy, 0, 4096 * sizeof(int), stream);
    quant_xy<<<5120, 256, 0, stream>>>(x, y, A8, B8T, rs, sy);
    gemm_i8<<<512, 256, 0, stream>>>(A8, B8T, rs, sy, out);
}

// Round 10
// 235.376 us; speedup vs baseline: 1.3427x; 1.0424x over previous
//
#include <hip/hip_runtime.h>
#include <cstdint>
#include <cstddef>

typedef int int32x4  __attribute__((ext_vector_type(4)));
typedef int int32x16 __attribute__((ext_vector_type(16)));

#define AS1 __attribute__((address_space(1)))
#define AS3 __attribute__((address_space(3)))

__device__ __forceinline__ void gload_lds16(const void* g, void* l) {
    __builtin_amdgcn_global_load_lds((const AS1 void*)g, (AS3 void*)l, 16, 0, 0);
}

#define MFMA_I8(a, b, c) __builtin_amdgcn_mfma_i32_32x32x32_i8((a), (b), (c), 0, 0, 0)

// ---------------------------------------------------------------------------
// Fused quant kernel (frozen r6 version).
// Blocks [0,4096): x-rows. Blocks [4096,5120): y 256n x 64k coalesced tiles.
// ---------------------------------------------------------------------------
__global__ __launch_bounds__(256) void quant_xy(const float* __restrict__ x,
                                                const float* __restrict__ y,
                                                signed char* __restrict__ A8,
                                                signed char* __restrict__ B8T,
                                                int* __restrict__ rs,
                                                int* __restrict__ sy) {
    const int t = threadIdx.x;
    if (blockIdx.x < 4096) {
        const int row = blockIdx.x;
        const float4* xr = (const float4*)(x + (size_t)row * 4096);
        char4* ar = (char4*)(A8 + (size_t)row * 4096);
        int s = 0;
#pragma unroll
        for (int i = 0; i < 4; i++) {
            const int idx = i * 256 + t;
            float4 v = xr[idx];
            int a0 = (int)v.x, a1 = (int)v.y, a2 = (int)v.z, a3 = (int)v.w;
            s += a0 + a1 + a2 + a3;
            char4 c;
            c.x = (signed char)a0; c.y = (signed char)a1;
            c.z = (signed char)a2; c.w = (signed char)a3;
            ar[idx] = c;
        }
#pragma unroll
        for (int off = 32; off > 0; off >>= 1) s += __shfl_down(s, off);
        __shared__ int wsum[4];
        if ((t & 63) == 0) wsum[t >> 6] = s;
        __syncthreads();
        if (t == 0) rs[row] = wsum[0] + wsum[1] + wsum[2] + wsum[3];
    } else {
        const int q = blockIdx.x - 4096;
        const int nt = (q & 15) * 256;
        const int kt = (q >> 4) * 64;
        __shared__ int tile_s[256 * 16];
        __shared__ int ssum[256];
        if (t < 256) ssum[t] = 0;
        __syncthreads();

        const int n4 = (t & 63) * 4;
        const int kg = (t >> 6) * 4;
        const int swzkey = t & 15;
        int s0 = 0, s1 = 0, s2 = 0, s3 = 0;
#pragma unroll
        for (int o = 0; o < 4; o++) {
            int b[4][4];
#pragma unroll
            for (int i = 0; i < 4; i++) {
                const int k = o * 16 + kg + i;
                float4 v = *(const float4*)(y + (size_t)(kt + k) * 4096 + nt + n4);
                b[i][0] = (int)v.x - 128; b[i][1] = (int)v.y - 128;
                b[i][2] = (int)v.z - 128; b[i][3] = (int)v.w - 128;
            }
            const int kd = o * 4 + (t >> 6);
            const int sw = kd ^ swzkey;
#pragma unroll
            for (int j = 0; j < 4; j++) {
                const int w = (b[0][j] & 255) | ((b[1][j] & 255) << 8) |
                              ((b[2][j] & 255) << 16) | (b[3][j] << 24);
                tile_s[(n4 + j) * 16 + sw] = w;
            }
            s0 += b[0][0] + b[1][0] + b[2][0] + b[3][0];
            s1 += b[0][1] + b[1][1] + b[2][1] + b[3][1];
            s2 += b[0][2] + b[1][2] + b[2][2] + b[3][2];
            s3 += b[0][3] + b[1][3] + b[2][3] + b[3][3];
        }
        atomicAdd(&ssum[n4 + 0], s0);
        atomicAdd(&ssum[n4 + 1], s1);
        atomicAdd(&ssum[n4 + 2], s2);
        atomicAdd(&ssum[n4 + 3], s3);
        __syncthreads();

        const int c = t & 3;
#pragma unroll
        for (int p = 0; p < 4; p++) {
            const int n = (t >> 2) + p * 64;
            const int key = (n >> 2) & 15;
            int32x4 o;
            o.x = tile_s[n * 16 + ((c * 4 + 0) ^ key)];
            o.y = tile_s[n * 16 + ((c * 4 + 1) ^ key)];
            o.z = tile_s[n * 16 + ((c * 4 + 2) ^ key)];
            o.w = tile_s[n * 16 + ((c * 4 + 3) ^ key)];
            *(int32x4*)(B8T + (size_t)(nt + n) * 4096 + kt + c * 16) = o;
        }
        if (t < 256) atomicAdd(&sy[nt + t], ssum[t]);
    }
}

// ---------------------------------------------------------------------------
// Kernel 3: int8 GEMM — BK=128 round (halve tile boundaries).
// Ledger: r0/r1/r3 schedules null; r2 small-tile ✗; r4 reg-pipeline best
// (82us, MfmaUtil 38.7); r7 A-from-global ✗; r9 block-TLP null (85.7, 36%).
// Invariant across all: ~3100 cyc/tile with MFMA 1171 + VALU 530 + ~1400
// unattributed wait; no pipe saturated. Hypothesis: fixed per-K-tile
// boundary cost (barrier skew + staging latency) that intra-tile schedule
// can't amortize. Test+fix: BK=128 on the r4 geometry -> 32 tiles not 64.
// Geometry: 256 blocks, 512 thr, tile 256x256, 8 waves 2Mx4N, wave tile
// 128x64; per tile 4 K-quarters (sub s in {0,1} x ks in {0,1}) of 8 MFMAs.
// LDS: 2-ring x (A 2x16KB + B 2x16KB) = 128KB; 64B rows, XOR chunk swizzle
// at global source (LDS dest linear, base + lane*16 — m104/m108, r8 lesson).
// Register frag pipeline (r4 mechanism): X frags feed even quarters, Y odd;
// each quarter's MFMAs run while the next quarter's frags are ds_read.
// Per-tile sync: q0 issues stage(t+1) [8 gloads] AFTER the tile-top (prior
// readers of that ring drained — enforced by lgkmcnt(0) at the q2 boundary);
// q2-boundary: s_waitcnt(vmcnt(0)+lgkmcnt(0)) + s_barrier => tile t+1 fully
// resident & published; q3 then prefetches X <- (t+1, s0, ks0) cross-tile.
// Only ONE barrier pair per 128-deep tile.
// Frags: A[m=lane&31][k=(lane>>5)*16+j]; C/D col=lane&31,
// row=(reg&3)+8*(reg>>2)+4*(lane>>5)  (verified r0-r9, absmax 32).
// Epilogue: C = 7.5e-4 * (P - 32*rs[m] + 66*sy[n] - 8650752)
// ---------------------------------------------------------------------------
__global__ __launch_bounds__(512, 2) void gemm_i8(const signed char* __restrict__ A8,
                                                  const signed char* __restrict__ B8T,
                                                  const int* __restrict__ rs,
                                                  const int* __restrict__ sy,
                                                  float* __restrict__ C) {
    __shared__ __align__(16) signed char As[2 * 32768];  // ring x (2 sub x 16KB)
    __shared__ __align__(16) signed char Bs[2 * 32768];
    const int tid = threadIdx.x;
    const int lin = blockIdx.x;
    const int til = (lin & 7) * 32 + (lin >> 3);   // XCD-contiguous tiles
    const int bm = (til >> 4) * 256;
    const int bn = (til & 15) * 256;
    const int lane = tid & 63;
    const int wave = tid >> 6;
    const int wm = (wave >> 2) * 128;   // 2 m-waves x 128
    const int wn = (wave & 3) * 64;     // 4 n-waves x 64
    const int mr = lane & 31;
    const int kh = lane >> 5;

    int32x16 acc[4][2] = {};

    // staging: thread -> row tid>>2 (+128p), source chunk (tid&3)^((tid>>3)&3);
    // dst = uniform base + tid*16 (+p*8192): matches global_load_lds layout.
    const size_t srowoff = (size_t)(tid >> 2) * 4096 +
                           (((tid & 3) ^ ((tid >> 3) & 3)) * 16);
    const size_t arow = (size_t)bm * 4096 + srowoff;
    const size_t brow = (size_t)bn * 4096 + srowoff;

    // fragment LDS offsets within a 16KB subtile: row*64 + slot*16,
    // slot = (ks*2+kh) ^ ((mr>>1)&3)
    int aoff[4][2], boff[2][2];
#pragma unroll
    for (int ks = 0; ks < 2; ks++) {
        const int slot = ((ks * 2 + kh) ^ ((mr >> 1) & 3)) * 16;
#pragma unroll
        for (int i = 0; i < 4; i++) aoff[i][ks] = (wm + i * 32 + mr) * 64 + slot;
#pragma unroll
        for (int j = 0; j < 2; j++) boff[j][ks] = (wn + j * 32 + mr) * 64 + slot;
    }

    auto stage = [&](int r, int kt) {   // 8 gloads: (2 sub x 2 p) x (A,B)
#pragma unroll
        for (int s = 0; s < 2; s++) {
            signed char* a_dst = As + r * 32768 + s * 16384 + tid * 16;
            signed char* b_dst = Bs + r * 32768 + s * 16384 + tid * 16;
#pragma unroll
            for (int p = 0; p < 2; p++) {
                gload_lds16(A8 + arow + (size_t)p * 524288 + kt + s * 64,
                            a_dst + p * 8192);
                gload_lds16(B8T + brow + (size_t)p * 524288 + kt + s * 64,
                            b_dst + p * 8192);
            }
        }
    };

    // waitcnt imm: vmcnt[3:0]=bits0-3, vmcnt[5:4]=bits14-15, exp=0x70 (ignore),
    // lgkm=bits8-11. 0xF70 = vmcnt(0), lgkm ignore. 0x070 = vmcnt(0)+lgkmcnt(0).
    stage(0, 0);
    __builtin_amdgcn_s_waitcnt(0xF70);
    __builtin_amdgcn_s_barrier();
    __builtin_amdgcn_sched_barrier(0);

    int32x4 xa[4], xb[2];   // frags for even quarters (q0, q2)
    int32x4 ya[4], yb[2];   // frags for odd quarters (q1, q3)
#pragma unroll
    for (int i = 0; i < 4; i++) xa[i] = *(const int32x4*)(As + aoff[i][0]);
#pragma unroll
    for (int j = 0; j < 2; j++) xb[j] = *(const int32x4*)(Bs + boff[j][0]);

#pragma unroll 1
    for (int t = 0; t < 32; ++t) {
        const signed char* Ac = As + (t & 1) * 32768;        // ring: tile t
        const signed char* Bc = Bs + (t & 1) * 32768;
        const signed char* An = As + ((t + 1) & 1) * 32768;  // ring: tile t+1
        const signed char* Bn = Bs + ((t + 1) & 1) * 32768;

        // ---- q0: read Y <- (t, s0, ks1); issue stage(t+1); MFMA X ----
#pragma unroll
        for (int i = 0; i < 4; i++) ya[i] = *(const int32x4*)(Ac + aoff[i][1]);
#pragma unroll
        for (int j = 0; j < 2; j++) yb[j] = *(const int32x4*)(Bc + boff[j][1]);
        if (t < 31) stage((t + 1) & 1, (t + 1) * 128);
        __builtin_amdgcn_sched_barrier(0);
        __builtin_amdgcn_s_setprio(1);
        acc[0][0] = MFMA_I8(xa[0], xb[0], acc[0][0]);
        acc[0][1] = MFMA_I8(xa[0], xb[1], acc[0][1]);
        acc[1][0] = MFMA_I8(xa[1], xb[0], acc[1][0]);
        acc[1][1] = MFMA_I8(xa[1], xb[1], acc[1][1]);
        acc[2][0] = MFMA_I8(xa[2], xb[0], acc[2][0]);
        acc[2][1] = MFMA_I8(xa[2], xb[1], acc[2][1]);
        acc[3][0] = MFMA_I8(xa[3], xb[0], acc[3][0]);
        acc[3][1] = MFMA_I8(xa[3], xb[1], acc[3][1]);
        __builtin_amdgcn_s_setprio(0);
        __builtin_amdgcn_sched_barrier(0);

        // ---- q1: read X <- (t, s1, ks0); MFMA Y ----
#pragma unroll
        for (int i = 0; i < 4; i++) xa[i] = *(const int32x4*)(Ac + 16384 + aoff[i][0]);
#pragma unroll
        for (int j = 0; j < 2; j++) xb[j] = *(const int32x4*)(Bc + 16384 + boff[j][0]);
        __builtin_amdgcn_sched_barrier(0);
        __builtin_amdgcn_s_setprio(1);
        acc[0][0] = MFMA_I8(ya[0], yb[0], acc[0][0]);
        acc[0][1] = MFMA_I8(ya[0], yb[1], acc[0][1]);
        acc[1][0] = MFMA_I8(ya[1], yb[0], acc[1][0]);
        acc[1][1] = MFMA_I8(ya[1], yb[1], acc[1][1]);
        acc[2][0] = MFMA_I8(ya[2], yb[0], acc[2][0]);
        acc[2][1] = MFMA_I8(ya[2], yb[1], acc[2][1]);
        acc[3][0] = MFMA_I8(ya[3], yb[0], acc[3][0]);
        acc[3][1] = MFMA_I8(ya[3], yb[1], acc[3][1]);
        __builtin_amdgcn_s_setprio(0);
        __builtin_amdgcn_sched_barrier(0);

        // ---- q2: read Y <- (t, s1, ks1); MFMA X ----
#pragma unroll
        for (int i = 0; i < 4; i++) ya[i] = *(const int32x4*)(Ac + 16384 + aoff[i][1]);
#pragma unroll
        for (int j = 0; j < 2; j++) yb[j] = *(const int32x4*)(Bc + 16384 + boff[j][1]);
        __builtin_amdgcn_sched_barrier(0);
        __builtin_amdgcn_s_setprio(1);
        acc[0][0] = MFMA_I8(xa[0], xb[0], acc[0][0]);
        acc[0][1] = MFMA_I8(xa[0], xb[1], acc[0][1]);
        acc[1][0] = MFMA_I8(xa[1], xb[0], acc[1][0]);
        acc[1][1] = MFMA_I8(xa[1], xb[1], acc[1][1]);
        acc[2][0] = MFMA_I8(xa[2], xb[0], acc[2][0]);
        acc[2][1] = MFMA_I8(xa[2], xb[1], acc[2][1]);
        acc[3][0] = MFMA_I8(xa[3], xb[0], acc[3][0]);
        acc[3][1] = MFMA_I8(xa[3], xb[1], acc[3][1]);
        __builtin_amdgcn_s_setprio(0);
        __builtin_amdgcn_sched_barrier(0);

        // ---- boundary: tile t+1 landed (own) + all reads of ring (t+1)&1
        //      drained (lgkm 0) -> barrier publishes both cross-wave ----
        __builtin_amdgcn_s_waitcnt(0x070);   // vmcnt(0) + lgkmcnt(0)
        __builtin_amdgcn_s_barrier();
        __builtin_amdgcn_sched_barrier(0);

        // ---- q3: read X <- (t+1, s0, ks0); MFMA Y ----
        if (t < 31) {
#pragma unroll
            for (int i = 0; i < 4; i++) xa[i] = *(const int32x4*)(An + aoff[i][0]);
#pragma unroll
            for (int j = 0; j < 2; j++) xb[j] = *(const int32x4*)(Bn + boff[j][0]);
        }
        __builtin_amdgcn_sched_barrier(0);
        __builtin_amdgcn_s_setprio(1);
        acc[0][0] = MFMA_I8(ya[0], yb[0], acc[0][0]);
        acc[0][1] = MFMA_I8(ya[0], yb[1], acc[0][1]);
        acc[1][0] = MFMA_I8(ya[1], yb[0], acc[1][0]);
        acc[1][1] = MFMA_I8(ya[1], yb[1], acc[1][1]);
        acc[2][0] = MFMA_I8(ya[2], yb[0], acc[2][0]);
        acc[2][1] = MFMA_I8(ya[2], yb[1], acc[2][1]);
        acc[3][0] = MFMA_I8(ya[3], yb[0], acc[3][0]);
        acc[3][1] = MFMA_I8(ya[3], yb[1], acc[3][1]);
        __builtin_amdgcn_s_setprio(0);
    }

    // Epilogue. C/D: col = lane&31, row = (reg&3) + 8*(reg>>2) + 4*kh
#pragma unroll
    for (int i = 0; i < 4; i++) {
#pragma unroll
        for (int r = 0; r < 16; r++) {
            const int gm = bm + wm + i * 32 + (r & 3) + 8 * (r >> 2) + 4 * kh;
            const int rcorr = -32 * rs[gm] - 8650752;
#pragma unroll
            for (int j = 0; j < 2; j++) {
                const int gn = bn + wn + j * 32 + mr;
                const int v = acc[i][j][r] + rcorr + 66 * sy[gn];
                C[(size_t)gm * 4096 + gn] = 7.5e-4f * (float)v;
            }
        }
    }
}

// ---------------------------------------------------------------------------
extern "C" void kernel_launch(void* const* d_in, const int* in_sizes, int n_in,
                              void* d_out, int out_size, void* d_ws, size_t ws_size,
                              hipStream_t stream) {
    const float* x = (const float*)d_in[0];  // [4096,4096] int8-valued
    const float* y = (const float*)d_in[1];  // [4096,4096] uint8-valued
    float* out = (float*)d_out;

    char* ws = (char*)d_ws;
    signed char* A8  = (signed char*)ws;                         // 16 MiB
    signed char* B8T = (signed char*)(ws + (16u << 20));         // 16 MiB
    int* rs = (int*)(ws + (32u << 20));                          // 16 KiB
    int* sy = (int*)(ws + (32u << 20) + (16u << 10));            // 16 KiB

    hipMemsetAsync(sy, 0, 4096 * sizeof(int), stream);
    quant_xy<<<5120, 256, 0, stream>>>(x, y, A8, B8T, rs, sy);
    gemm_i8<<<256, 512, 0, stream>>>(A8, B8T, rs, sy, out);
}